// Round 5
// baseline (440.170 us; speedup 1.0000x reference)
//
#include <hip/hip_runtime.h>

#define L 1024
#define BLOCK 256   // 4 waves, 1 row per wave

// native clang vector type: __builtin_nontemporal_* accepts these
// (HIP_vector_type float4 is a struct and is rejected)
typedef float floatx4 __attribute__((ext_vector_type(4)));

__device__ __forceinline__ float soft_thr(float c, float thr) {
    float a = fabsf(c);
    return (a >= thr) ? copysignf(a - thr, c) : 0.0f;
}

__device__ __forceinline__ int imin2(int a, int b) { return (a < b) ? a : b; }
__device__ __forceinline__ int imax2(int a, int b) { return (a > b) ? a : b; }

// __launch_bounds__(256, 8): 8 waves/EU -> allocator targets <=64 VGPR (8-wave
// occupancy bracket). Streaming kernel: all global accesses are nontemporal
// (nt flag) since input is read-once and output is write-once, 512 MiB
// footprint > 256 MiB L3 -> avoid cache pollution.
__global__ __launch_bounds__(BLOCK, 8) void wavelet_denoise_kernel(
        const float* __restrict__ x, float* __restrict__ out) {
    constexpr float IS2 = 0.70710678118654752f;
    constexpr float SQRT_2LOGL = 3.7232974111f;   // f32(sqrt(2*ln(1024)))

    const int lane = threadIdx.x & 63;
    const int wid  = threadIdx.x >> 6;
    const long long row = (long long)blockIdx.x * 4 + wid;
    const float* xr = x + row * L;
    float* orow = out + row * L;

    // ---- load: 4 coalesced 16B chunks (nontemporal)
    floatx4 in[4];
    #pragma unroll
    for (int j = 0; j < 4; ++j)
        in[j] = __builtin_nontemporal_load(((const floatx4*)xr) + j * 64 + lane);

    // ---- level 1 + fused level 2
    float cd1[8];
    float ca2[4], cd2[4];
    #pragma unroll
    for (int j = 0; j < 4; ++j) {
        float a0 = (in[j].x + in[j].y) * IS2;
        float a1 = (in[j].z + in[j].w) * IS2;
        cd1[2*j]   = (in[j].x - in[j].y) * IS2;
        cd1[2*j+1] = (in[j].z - in[j].w) * IS2;
        ca2[j] = (a0 + a1) * IS2;
        cd2[j] = (a0 - a1) * IS2;
    }

    // ---- level 3: adjacent-lane combine; even lane 2m holds ca3/cd3[32j + m]
    float ca3[4], cd3[4];
    #pragma unroll
    for (int j = 0; j < 4; ++j) {
        float o = __shfl_xor(ca2[j], 1);
        ca3[j] = (ca2[j] + o) * IS2;   // valid on even lanes (odd: unused garbage)
        cd3[j] = (ca2[j] - o) * IS2;
    }

    // ---- exact median of 512 |cd1| -------------------------------------------
    // Direction-encoded integer bitonic: keys = bit patterns of |cd1| (monotone
    // as signed int for non-negative floats); per-element sort direction for
    // k>=8 depends only on lane bits, folded into the key via XOR masks so every
    // compare-exchange is plain min/max. Final k=512 phase truncated to the
    // j=256 split: sorted[255] = max(lower 256), sorted[256] = min(upper 256).
    int w[8];
    const int b0 = -(int)( lane       & 1);
    const int b1 = -(int)((lane >> 1) & 1);
    const int b2 = -(int)((lane >> 2) & 1);
    const int b3 = -(int)((lane >> 3) & 1);
    const int b4 = -(int)((lane >> 4) & 1);
    const int b5 = -(int)((lane >> 5) & 1);

    #pragma unroll
    for (int r = 0; r < 8; ++r)
        w[r] = (__float_as_int(cd1[r]) & 0x7fffffff) ^ b0;

    #define CE(a, c) { int _lo = imin2(w[a], w[c]); int _hi = imax2(w[a], w[c]); \
                       w[a] = _lo; w[c] = _hi; }

    // in-lane Batcher odd-even mergesort of 8 (19 CEs), ascending in w-space
    CE(0,1) CE(2,3) CE(4,5) CE(6,7)
    CE(0,2) CE(1,3) CE(4,6) CE(5,7)
    CE(1,2) CE(5,6)
    CE(0,4) CE(1,5) CE(2,6) CE(3,7)
    CE(2,4) CE(3,5)
    CE(1,2) CE(3,4) CE(5,6)

    #define XORW(T) { const int _t = (T); \
        _Pragma("unroll") for (int r = 0; r < 8; ++r) w[r] ^= _t; }

    #define CROSS_STAGE(LM) { const bool _up = (lane & (LM)) != 0; \
        _Pragma("unroll") for (int r = 0; r < 8; ++r) { \
            int _o = __shfl_xor(w[r], (LM)); \
            w[r] = _up ? imax2(w[r], _o) : imin2(w[r], _o); } }

    #define INLANE3() { \
        CE(0,4) CE(1,5) CE(2,6) CE(3,7) \
        CE(0,2) CE(1,3) CE(4,6) CE(5,7) \
        CE(0,1) CE(2,3) CE(4,5) CE(6,7) }

    XORW(b0 ^ b1); CROSS_STAGE(1);                                                             INLANE3();  // k=16
    XORW(b1 ^ b2); CROSS_STAGE(2);  CROSS_STAGE(1);                                            INLANE3();  // k=32
    XORW(b2 ^ b3); CROSS_STAGE(4);  CROSS_STAGE(2); CROSS_STAGE(1);                            INLANE3();  // k=64
    XORW(b3 ^ b4); CROSS_STAGE(8);  CROSS_STAGE(4); CROSS_STAGE(2); CROSS_STAGE(1);            INLANE3();  // k=128
    XORW(b4 ^ b5); CROSS_STAGE(16); CROSS_STAGE(8); CROSS_STAGE(4); CROSS_STAGE(2); CROSS_STAGE(1); INLANE3();  // k=256
    XORW(b5);      CROSS_STAGE(32);   // k=512 bitonic split only (back in u-space)

    // ranks 255/256: max of lower 256 / min of upper 256
    int zmx = imax2(imax2(imax2(w[0], w[1]), imax2(w[2], w[3])),
                    imax2(imax2(w[4], w[5]), imax2(w[6], w[7])));
    int zmn = imin2(imin2(imin2(w[0], w[1]), imin2(w[2], w[3])),
                    imin2(imin2(w[4], w[5]), imin2(w[6], w[7])));
    int z = (lane & 32) ? ~zmn : zmx;   // upper half reduces min via ~ trick
    #pragma unroll
    for (int m = 1; m <= 16; m <<= 1)
        z = imax2(z, __shfl_xor(z, m));
    const float m0 = __int_as_float(__shfl(z, 0));      // sorted[255]
    const float m1 = __int_as_float(~__shfl(z, 32));    // sorted[256]

    #undef CE
    #undef XORW
    #undef CROSS_STAGE
    #undef INLANE3

    const float median = 0.5f * (m0 + m1);
    const float lam  = (median / 0.6745f) * SQRT_2LOGL;
    const float thr1 = lam;                      // / log2(2)
    const float thr2 = lam / 1.5849625007f;      // / log2(3)
    const float thr3 = lam * 0.5f;               // / log2(4)

    // ---- reconstruction (all local / single shuffle per level-3 fetch)
    #pragma unroll
    for (int j = 0; j < 4; ++j) {
        float c3 = __shfl(ca3[j], lane & 62);
        float d3 = soft_thr(__shfl(cd3[j], lane & 62), thr3);
        float ca2r = ((lane & 1) == 0) ? (c3 + d3) * IS2 : (c3 - d3) * IS2;

        float d2 = soft_thr(cd2[j], thr2);
        float ca1r0 = (ca2r + d2) * IS2;
        float ca1r1 = (ca2r - d2) * IS2;

        float d10 = soft_thr(cd1[2*j],   thr1);
        float d11 = soft_thr(cd1[2*j+1], thr1);
        floatx4 o;
        o.x = (ca1r0 + d10) * IS2;
        o.y = (ca1r0 - d10) * IS2;
        o.z = (ca1r1 + d11) * IS2;
        o.w = (ca1r1 - d11) * IS2;
        __builtin_nontemporal_store(o, ((floatx4*)orow) + j * 64 + lane);
    }
}

extern "C" void kernel_launch(void* const* d_in, const int* in_sizes, int n_in,
                              void* d_out, int out_size, void* d_ws, size_t ws_size,
                              hipStream_t stream) {
    const float* x = (const float*)d_in[0];
    float* out = (float*)d_out;
    const int rows = in_sizes[0] / L;           // 65536
    wavelet_denoise_kernel<<<rows / 4, BLOCK, 0, stream>>>(x, out);
}

// Round 6
// 424.772 us; speedup vs baseline: 1.0362x; 1.0362x over previous
//
#include <hip/hip_runtime.h>

#define L 1024
#define BLOCK 256   // 4 waves, 1 row per wave

// native clang vector types
typedef float floatx4 __attribute__((ext_vector_type(4)));
typedef unsigned int uintx2 __attribute__((ext_vector_type(2)));

__device__ __forceinline__ float soft_thr(float c, float thr) {
    float a = fabsf(c);
    return (a >= thr) ? copysignf(a - thr, c) : 0.0f;
}

__device__ __forceinline__ int imin2(int a, int b) { return (a < b) ? a : b; }
__device__ __forceinline__ int imax2(int a, int b) { return (a > b) ? a : b; }

// DPP transport (VALU pipe — NOT the CU-shared LDS pipe that __shfl uses).
// ctrl: 0xB1 = quad_perm xor1, 0x4E = xor2, 0x1B = quad reverse (xor3),
// 0x141 = row_half_mirror (xor7 within 8), 0x128 = row_ror:8 (xor8 within 16),
// 0xA0 = quad_perm [0,0,2,2] (broadcast even lane of each pair).
template<int CTRL>
__device__ __forceinline__ int dppmv(int v) {
    return __builtin_amdgcn_update_dpp(v, v, CTRL, 0xF, 0xF, true);
}
// xor4 within 16 = xor7 then xor3 (two DPP movs)
__device__ __forceinline__ int dpp_xor4(int v) {
    return dppmv<0x1B>(dppmv<0x141>(v));
}
// gfx950 permlane swaps: with both operands equal, the result pair is the SET
// {self, partner(lane^16 / lane^32)} in every lane — min/max over the pair is
// direction-agnostic, no select needed.
__device__ __forceinline__ uintx2 pl16(int v) {
    return __builtin_amdgcn_permlane16_swap((unsigned)v, (unsigned)v, false, false);
}
__device__ __forceinline__ uintx2 pl32(int v) {
    return __builtin_amdgcn_permlane32_swap((unsigned)v, (unsigned)v, false, false);
}

// __launch_bounds__(256, 8): 8 waves/EU -> allocator targets <=64 VGPR.
// Streaming kernel (512 MiB footprint > L3): nontemporal loads/stores.
// All cross-lane exchange is DPP/permlane/readlane: zero LDS-pipe traffic.
__global__ __launch_bounds__(BLOCK, 8) void wavelet_denoise_kernel(
        const float* __restrict__ x, float* __restrict__ out) {
    constexpr float IS2 = 0.70710678118654752f;
    constexpr float SQRT_2LOGL = 3.7232974111f;   // f32(sqrt(2*ln(1024)))

    const int lane = threadIdx.x & 63;
    const int wid  = threadIdx.x >> 6;
    const long long row = (long long)blockIdx.x * 4 + wid;
    const float* xr = x + row * L;
    float* orow = out + row * L;

    // ---- load: 4 coalesced 16B chunks (nontemporal)
    floatx4 in[4];
    #pragma unroll
    for (int j = 0; j < 4; ++j)
        in[j] = __builtin_nontemporal_load(((const floatx4*)xr) + j * 64 + lane);

    // ---- level 1 + fused level 2
    float cd1[8];
    float ca2[4], cd2[4];
    #pragma unroll
    for (int j = 0; j < 4; ++j) {
        float a0 = (in[j].x + in[j].y) * IS2;
        float a1 = (in[j].z + in[j].w) * IS2;
        cd1[2*j]   = (in[j].x - in[j].y) * IS2;
        cd1[2*j+1] = (in[j].z - in[j].w) * IS2;
        ca2[j] = (a0 + a1) * IS2;
        cd2[j] = (a0 - a1) * IS2;
    }

    // ---- level 3: adjacent-lane combine via DPP xor1
    float ca3[4], cd3[4];
    #pragma unroll
    for (int j = 0; j < 4; ++j) {
        float o = __int_as_float(dppmv<0xB1>(__float_as_int(ca2[j])));
        ca3[j] = (ca2[j] + o) * IS2;   // valid on even lanes (odd: unused garbage)
        cd3[j] = (ca2[j] - o) * IS2;
    }

    // ---- exact median of 512 |cd1| -------------------------------------------
    // Direction-encoded integer bitonic (keys = |cd1| bit patterns, monotone as
    // signed int; per-lane sort direction folded in via XOR masks). All
    // cross-lane compare-exchanges ride the VALU pipe (DPP / permlane_swap).
    // Final k=512 phase truncated at the j=256 split:
    //   sorted[255] = max(lower 256), sorted[256] = min(upper 256).
    int w[8];
    const int b0 = -(int)( lane       & 1);
    const int b1 = -(int)((lane >> 1) & 1);
    const int b2 = -(int)((lane >> 2) & 1);
    const int b3 = -(int)((lane >> 3) & 1);
    const int b4 = -(int)((lane >> 4) & 1);
    const int b5 = -(int)((lane >> 5) & 1);

    #pragma unroll
    for (int r = 0; r < 8; ++r)
        w[r] = (__float_as_int(cd1[r]) & 0x7fffffff) ^ b0;

    #define CE(a, c) { int _lo = imin2(w[a], w[c]); int _hi = imax2(w[a], w[c]); \
                       w[a] = _lo; w[c] = _hi; }

    // in-lane Batcher odd-even mergesort of 8 (19 CEs), ascending in w-space
    CE(0,1) CE(2,3) CE(4,5) CE(6,7)
    CE(0,2) CE(1,3) CE(4,6) CE(5,7)
    CE(1,2) CE(5,6)
    CE(0,4) CE(1,5) CE(2,6) CE(3,7)
    CE(2,4) CE(3,5)
    CE(1,2) CE(3,4) CE(5,6)

    #define XORW(T) { const int _t = (T); \
        _Pragma("unroll") for (int r = 0; r < 8; ++r) w[r] ^= _t; }

    // cross-lane stages: partner fetched on the VALU pipe
    #define CS_DPP(LM, CTRL) { const bool _up = (lane & (LM)) != 0; \
        _Pragma("unroll") for (int r = 0; r < 8; ++r) { \
            int _p = dppmv<CTRL>(w[r]); \
            w[r] = _up ? imax2(w[r], _p) : imin2(w[r], _p); } }

    #define CS_XOR4() { const bool _up = (lane & 4) != 0; \
        _Pragma("unroll") for (int r = 0; r < 8; ++r) { \
            int _p = dpp_xor4(w[r]); \
            w[r] = _up ? imax2(w[r], _p) : imin2(w[r], _p); } }

    #define CS_PL16() { const bool _up = (lane & 16) != 0; \
        _Pragma("unroll") for (int r = 0; r < 8; ++r) { \
            uintx2 _q = pl16(w[r]); \
            w[r] = _up ? imax2((int)_q.x, (int)_q.y) : imin2((int)_q.x, (int)_q.y); } }

    #define CS_PL32() { const bool _up = (lane & 32) != 0; \
        _Pragma("unroll") for (int r = 0; r < 8; ++r) { \
            uintx2 _q = pl32(w[r]); \
            w[r] = _up ? imax2((int)_q.x, (int)_q.y) : imin2((int)_q.x, (int)_q.y); } }

    #define INLANE3() { \
        CE(0,4) CE(1,5) CE(2,6) CE(3,7) \
        CE(0,2) CE(1,3) CE(4,6) CE(5,7) \
        CE(0,1) CE(2,3) CE(4,5) CE(6,7) }

    XORW(b0 ^ b1); CS_DPP(1, 0xB1);                                                   INLANE3();  // k=16
    XORW(b1 ^ b2); CS_DPP(2, 0x4E); CS_DPP(1, 0xB1);                                  INLANE3();  // k=32
    XORW(b2 ^ b3); CS_XOR4();       CS_DPP(2, 0x4E); CS_DPP(1, 0xB1);                 INLANE3();  // k=64
    XORW(b3 ^ b4); CS_DPP(8, 0x128); CS_XOR4(); CS_DPP(2, 0x4E); CS_DPP(1, 0xB1);     INLANE3();  // k=128
    XORW(b4 ^ b5); CS_PL16(); CS_DPP(8, 0x128); CS_XOR4(); CS_DPP(2, 0x4E); CS_DPP(1, 0xB1); INLANE3();  // k=256
    XORW(b5);      CS_PL32();   // k=512 bitonic split only (back in u-space)

    // ranks 255/256: max of lower 256 / min of upper 256
    int zmx = imax2(imax2(imax2(w[0], w[1]), imax2(w[2], w[3])),
                    imax2(imax2(w[4], w[5]), imax2(w[6], w[7])));
    int zmn = imin2(imin2(imin2(w[0], w[1]), imin2(w[2], w[3])),
                    imin2(imin2(w[4], w[5]), imin2(w[6], w[7])));
    int z = (lane & 32) ? ~zmn : zmx;   // upper half reduces min via ~ trick
    // all-reduce max within each 32-lane half, all on VALU
    z = imax2(z, dppmv<0xB1>(z));
    z = imax2(z, dppmv<0x4E>(z));
    z = imax2(z, dpp_xor4(z));
    z = imax2(z, dppmv<0x128>(z));
    { uintx2 q = pl16(z); z = imax2((int)q.x, (int)q.y); }
    const float m0 = __int_as_float(__builtin_amdgcn_readlane(z, 0));    // sorted[255]
    const float m1 = __int_as_float(~__builtin_amdgcn_readlane(z, 32));  // sorted[256]

    #undef CE
    #undef XORW
    #undef CS_DPP
    #undef CS_XOR4
    #undef CS_PL16
    #undef CS_PL32
    #undef INLANE3

    const float median = 0.5f * (m0 + m1);
    const float lam  = (median / 0.6745f) * SQRT_2LOGL;
    const float thr1 = lam;                      // / log2(2)
    const float thr2 = lam / 1.5849625007f;      // / log2(3)
    const float thr3 = lam * 0.5f;               // / log2(4)

    // ---- reconstruction; pair-broadcast via DPP quad_perm [0,0,2,2] (0xA0)
    #pragma unroll
    for (int j = 0; j < 4; ++j) {
        float c3 = __int_as_float(dppmv<0xA0>(__float_as_int(ca3[j])));
        float d3 = soft_thr(__int_as_float(dppmv<0xA0>(__float_as_int(cd3[j]))), thr3);
        float ca2r = ((lane & 1) == 0) ? (c3 + d3) * IS2 : (c3 - d3) * IS2;

        float d2 = soft_thr(cd2[j], thr2);
        float ca1r0 = (ca2r + d2) * IS2;
        float ca1r1 = (ca2r - d2) * IS2;

        float d10 = soft_thr(cd1[2*j],   thr1);
        float d11 = soft_thr(cd1[2*j+1], thr1);
        floatx4 o;
        o.x = (ca1r0 + d10) * IS2;
        o.y = (ca1r0 - d10) * IS2;
        o.z = (ca1r1 + d11) * IS2;
        o.w = (ca1r1 - d11) * IS2;
        __builtin_nontemporal_store(o, ((floatx4*)orow) + j * 64 + lane);
    }
}

extern "C" void kernel_launch(void* const* d_in, const int* in_sizes, int n_in,
                              void* d_out, int out_size, void* d_ws, size_t ws_size,
                              hipStream_t stream) {
    const float* x = (const float*)d_in[0];
    float* out = (float*)d_out;
    const int rows = in_sizes[0] / L;           // 65536
    wavelet_denoise_kernel<<<rows / 4, BLOCK, 0, stream>>>(x, out);
}